// Round 1
// baseline (750.294 us; speedup 1.0000x reference)
//
#include <hip/hip_runtime.h>
#include <math.h>

constexpr int F_IN  = 128;
constexpr int H_MID = 16;
constexpr int C_OUT = 10;

// ---------------- degree / norm ----------------
__global__ void k_deg_init(float* __restrict__ deg, int N) {
  int i = blockIdx.x * blockDim.x + threadIdx.x;
  if (i < N) deg[i] = 1.0f;  // self-loop
}

__global__ void k_deg_count(const int* __restrict__ dst, float* __restrict__ deg, int E) {
  int e = blockIdx.x * blockDim.x + threadIdx.x;
  if (e < E) atomicAdd(&deg[dst[e]], 1.0f);
}

__global__ void k_dinv(float* __restrict__ deg, int N) {
  int i = blockIdx.x * blockDim.x + threadIdx.x;
  if (i < N) deg[i] = rsqrtf(deg[i]);  // deg >= 1 always
}

// ---------------- m = (x2 @ W1) * dinv[row];  agg initialized to m (self-loop term) ----
// block = 256 threads, 64 rows/block, thread t -> (row_local = t>>2, j0 = (t&3)*4)
__global__ __launch_bounds__(256) void k_gemv16(
    const float* __restrict__ x, const float* __restrict__ W,
    const float* __restrict__ dinv, float* __restrict__ m,
    float* __restrict__ agg, int N) {
  __shared__ float ws[F_IN * H_MID];   // 8 KB
  __shared__ float xs[64 * 132];       // pad 128->132 to break bank aliasing
  const int t = threadIdx.x;
  for (int i = t; i < F_IN * H_MID; i += 256) ws[i] = W[i];
  const int row0 = blockIdx.x * 64;
  const int rows = min(64, N - row0);
  const float4* xg = (const float4*)(x + (size_t)row0 * F_IN);
  for (int i = t; i < rows * 32; i += 256) {
    int rl = i >> 5, c = i & 31;
    float4 v = xg[rl * 32 + c];
    *(float4*)&xs[rl * 132 + c * 4] = v;
  }
  __syncthreads();
  const int rl = t >> 2;
  const int j0 = (t & 3) * 4;
  if (rl < rows) {
    float a0 = 0.f, a1 = 0.f, a2 = 0.f, a3 = 0.f;
    const float* xr = &xs[rl * 132];
    #pragma unroll
    for (int k = 0; k < F_IN; ++k) {
      const float xv = xr[k];
      const float* wr = &ws[k * H_MID + j0];
      a0 = fmaf(xv, wr[0], a0);
      a1 = fmaf(xv, wr[1], a1);
      a2 = fmaf(xv, wr[2], a2);
      a3 = fmaf(xv, wr[3], a3);
    }
    const int row = row0 + rl;
    const float dv = dinv[row];
    float4 o = make_float4(a0 * dv, a1 * dv, a2 * dv, a3 * dv);
    *(float4*)&m[(size_t)row * H_MID + j0]   = o;
    *(float4*)&agg[(size_t)row * H_MID + j0] = o;  // self-loop init
  }
}

// ---------------- edge scatter, 16 feats ----------------
__global__ void k_scatter16(const int* __restrict__ src, const int* __restrict__ dst,
                            const float* __restrict__ m, float* __restrict__ agg,
                            unsigned E) {
  unsigned t = blockIdx.x * 256u + threadIdx.x;
  if (t >= E * 16u) return;
  unsigned e = t >> 4, j = t & 15u;
  int s = src[e], d = dst[e];
  atomicAdd(&agg[(size_t)d * 16u + j], m[(size_t)s * 16u + j]);
}

// ---------------- h2 = relu(agg*dinv + b1); g = (h2 @ Wend)*dinv; oagg = g ----------
__global__ __launch_bounds__(256) void k_mid(
    const float* __restrict__ agg, const float* __restrict__ dinv,
    const float* __restrict__ b1, const float* __restrict__ Wend,
    float* __restrict__ g, float* __restrict__ oagg, int N) {
  __shared__ float ws[H_MID * C_OUT];
  __shared__ float bs[H_MID];
  const int t = threadIdx.x;
  if (t < H_MID * C_OUT) ws[t] = Wend[t];
  if (t < H_MID) bs[t] = b1[t];
  __syncthreads();
  const int n = blockIdx.x * 256 + t;
  if (n >= N) return;
  const float dv = dinv[n];
  float h[H_MID];
  const float4* ag = (const float4*)(agg + (size_t)n * H_MID);
  #pragma unroll
  for (int q = 0; q < 4; ++q) {
    float4 v = ag[q];
    h[4*q+0] = fmaxf(fmaf(v.x, dv, bs[4*q+0]), 0.f);
    h[4*q+1] = fmaxf(fmaf(v.y, dv, bs[4*q+1]), 0.f);
    h[4*q+2] = fmaxf(fmaf(v.z, dv, bs[4*q+2]), 0.f);
    h[4*q+3] = fmaxf(fmaf(v.w, dv, bs[4*q+3]), 0.f);
  }
  float o[C_OUT];
  #pragma unroll
  for (int j = 0; j < C_OUT; ++j) {
    float a = 0.f;
    #pragma unroll
    for (int k = 0; k < H_MID; ++k) a = fmaf(h[k], ws[k * C_OUT + j], a);
    o[j] = a * dv;
  }
  float2* gp = (float2*)(g    + (size_t)n * C_OUT);
  float2* op = (float2*)(oagg + (size_t)n * C_OUT);
  #pragma unroll
  for (int q = 0; q < 5; ++q) {
    float2 v = make_float2(o[2*q], o[2*q+1]);
    gp[q] = v;
    op[q] = v;  // self-loop init
  }
}

// ---------------- edge scatter, 10 feats (all lanes active via /10) ----------------
__global__ void k_scatter10(const int* __restrict__ src, const int* __restrict__ dst,
                            const float* __restrict__ g, float* __restrict__ oagg,
                            unsigned E) {
  unsigned t = blockIdx.x * 256u + threadIdx.x;
  if (t >= E * 10u) return;
  unsigned e = t / 10u;
  unsigned j = t - e * 10u;
  int s = src[e], d = dst[e];
  atomicAdd(&oagg[(size_t)d * 10u + j], g[(size_t)s * 10u + j]);
}

// ---------------- out = log_softmax(oagg*dinv + bend) ----------------
__global__ void k_final(const float* __restrict__ oagg, const float* __restrict__ dinv,
                        const float* __restrict__ bend, float* __restrict__ out, int N) {
  __shared__ float bs[C_OUT];
  if (threadIdx.x < C_OUT) bs[threadIdx.x] = bend[threadIdx.x];
  __syncthreads();
  int n = blockIdx.x * 256 + threadIdx.x;
  if (n >= N) return;
  const float dv = dinv[n];
  float v[C_OUT];
  const float2* ip = (const float2*)(oagg + (size_t)n * C_OUT);
  #pragma unroll
  for (int q = 0; q < 5; ++q) {
    float2 w = ip[q];
    v[2*q]   = fmaf(w.x, dv, bs[2*q]);
    v[2*q+1] = fmaf(w.y, dv, bs[2*q+1]);
  }
  float mx = -INFINITY;
  #pragma unroll
  for (int j = 0; j < C_OUT; ++j) mx = fmaxf(mx, v[j]);
  float s = 0.f;
  #pragma unroll
  for (int j = 0; j < C_OUT; ++j) s += __expf(v[j] - mx);
  const float ls = __logf(s) + mx;
  float2* op = (float2*)(out + (size_t)n * C_OUT);
  #pragma unroll
  for (int q = 0; q < 5; ++q)
    op[q] = make_float2(v[2*q] - ls, v[2*q+1] - ls);
}

extern "C" void kernel_launch(void* const* d_in, const int* in_sizes, int n_in,
                              void* d_out, int out_size, void* d_ws, size_t ws_size,
                              hipStream_t stream) {
  // inputs: 0=x1 1=x2 2=W1 3=b1 4=W_end 5=b_end 6=edge_index1 7=edge_index2 8=skip
  // NOTE: x1/edge_index1/skip are dead w.r.t. the returned output.
  const float* x2   = (const float*)d_in[1];
  const float* W1   = (const float*)d_in[2];
  const float* b1   = (const float*)d_in[3];
  const float* Wend = (const float*)d_in[4];
  const float* bend = (const float*)d_in[5];
  const int*   ei2  = (const int*)d_in[7];
  const int N = in_sizes[1] / F_IN;
  const int E = in_sizes[7] / 2;
  const int* src = ei2;
  const int* dst = ei2 + E;

  char* base = (char*)d_ws;
  size_t off = 0;
  auto alloc = [&](size_t elems) -> float* {
    float* p = (float*)(base + off);
    off += ((elems * sizeof(float) + 255) / 256) * 256;
    return p;
  };
  float* dinv = alloc((size_t)N);            // deg -> dinv in place
  float* m    = alloc((size_t)N * H_MID);
  float* agg  = alloc((size_t)N * H_MID);
  float* g    = alloc((size_t)N * C_OUT);
  float* oagg = alloc((size_t)N * C_OUT);

  const dim3 blk(256);
  const int gN = (N + 255) / 256;

  hipLaunchKernelGGL(k_deg_init,  dim3(gN), blk, 0, stream, dinv, N);
  hipLaunchKernelGGL(k_deg_count, dim3((E + 255) / 256), blk, 0, stream, dst, dinv, E);
  hipLaunchKernelGGL(k_dinv,      dim3(gN), blk, 0, stream, dinv, N);
  hipLaunchKernelGGL(k_gemv16,    dim3((N + 63) / 64), blk, 0, stream, x2, W1, dinv, m, agg, N);
  {
    unsigned nt = (unsigned)E * 16u;
    hipLaunchKernelGGL(k_scatter16, dim3((nt + 255) / 256), blk, 0, stream, src, dst, m, agg, (unsigned)E);
  }
  hipLaunchKernelGGL(k_mid, dim3(gN), blk, 0, stream, agg, dinv, b1, Wend, g, oagg, N);
  {
    unsigned nt = (unsigned)E * 10u;
    hipLaunchKernelGGL(k_scatter10, dim3((nt + 255) / 256), blk, 0, stream, src, dst, g, oagg, (unsigned)E);
  }
  hipLaunchKernelGGL(k_final, dim3(gN), blk, 0, stream, oagg, dinv, bend, (float*)d_out, N);
}

// Round 2
// 548.608 us; speedup vs baseline: 1.3676x; 1.3676x over previous
//
#include <hip/hip_runtime.h>
#include <math.h>

constexpr int F_IN  = 128;
constexpr int H_MID = 16;
constexpr int C_OUT = 10;
constexpr int SCAN_ITEMS = 8;
constexpr int SCAN_BLOCK = 256;
constexpr int SCAN_TILE  = SCAN_ITEMS * SCAN_BLOCK;  // 2048

// ---------------- CSR build: deg -> scan -> fill ----------------
__global__ void k_zero(int* __restrict__ p, int n) {
  int i = blockIdx.x * 256 + threadIdx.x;
  if (i < n) p[i] = 0;
}

__global__ void k_deg_count(const int* __restrict__ dst, int* __restrict__ deg, int E) {
  int e = blockIdx.x * 256 + threadIdx.x;
  if (e < E) atomicAdd(&deg[dst[e]], 1);
}

// block-level exclusive scan of deg into rowptr; also dinv = rsqrt(deg+1) (self-loop)
__global__ __launch_bounds__(SCAN_BLOCK) void k_scan1(
    const int* __restrict__ deg, int* __restrict__ rowptr,
    float* __restrict__ dinv, int* __restrict__ bsum, int N) {
  __shared__ int sh[SCAN_BLOCK];
  const int t = threadIdx.x;
  const int base = blockIdx.x * SCAN_TILE + t * SCAN_ITEMS;
  int v[SCAN_ITEMS];
  int s = 0;
  #pragma unroll
  for (int q = 0; q < SCAN_ITEMS; ++q) {
    int i = base + q;
    int d = (i < N) ? deg[i] : 0;
    v[q] = d; s += d;
  }
  sh[t] = s; __syncthreads();
  for (int off = 1; off < SCAN_BLOCK; off <<= 1) {
    int y = (t >= off) ? sh[t - off] : 0;
    __syncthreads();
    sh[t] += y;
    __syncthreads();
  }
  int run = sh[t] - s;  // exclusive prefix of this thread's chunk
  #pragma unroll
  for (int q = 0; q < SCAN_ITEMS; ++q) {
    int i = base + q;
    if (i < N) {
      rowptr[i] = run;
      dinv[i] = rsqrtf((float)(v[q] + 1));
    }
    run += v[q];
  }
  if (t == SCAN_BLOCK - 1) bsum[blockIdx.x] = sh[t];
}

__global__ void k_scan2(int* __restrict__ bsum, int nb) {
  if (blockIdx.x == 0 && threadIdx.x == 0) {
    int run = 0;
    for (int i = 0; i < nb; ++i) { int x = bsum[i]; bsum[i] = run; run += x; }
  }
}

__global__ void k_scan3(int* __restrict__ rowptr, const int* __restrict__ bsum,
                        int* __restrict__ cursor, int N, int E) {
  int i = blockIdx.x * 256 + threadIdx.x;
  if (i < N) {
    rowptr[i] += bsum[i / SCAN_TILE];
    cursor[i] = 0;
  }
  if (i == 0) rowptr[N] = E;
}

__global__ void k_fill(const int* __restrict__ src, const int* __restrict__ dst,
                       const int* __restrict__ rowptr, int* __restrict__ cursor,
                       int* __restrict__ adj, int E) {
  int e = blockIdx.x * 256 + threadIdx.x;
  if (e < E) {
    int d = dst[e];
    int pos = atomicAdd(&cursor[d], 1);
    adj[rowptr[d] + pos] = src[e];
  }
}

// ---------------- m = (x2 @ W1) * dinv[row] ----------------
__global__ __launch_bounds__(256) void k_gemv16(
    const float* __restrict__ x, const float* __restrict__ W,
    const float* __restrict__ dinv, float* __restrict__ m, int N) {
  __shared__ float ws[F_IN * H_MID];   // 8 KB
  __shared__ float xs[64 * 132];       // pad 128->132
  const int t = threadIdx.x;
  for (int i = t; i < F_IN * H_MID; i += 256) ws[i] = W[i];
  const int row0 = blockIdx.x * 64;
  const int rows = min(64, N - row0);
  const float4* xg = (const float4*)(x + (size_t)row0 * F_IN);
  for (int i = t; i < rows * 32; i += 256) {
    int rl = i >> 5, c = i & 31;
    float4 v = xg[rl * 32 + c];
    *(float4*)&xs[rl * 132 + c * 4] = v;
  }
  __syncthreads();
  const int rl = t >> 2;
  const int j0 = (t & 3) * 4;
  if (rl < rows) {
    float a0 = 0.f, a1 = 0.f, a2 = 0.f, a3 = 0.f;
    const float* xr = &xs[rl * 132];
    #pragma unroll
    for (int k = 0; k < F_IN; ++k) {
      const float xv = xr[k];
      const float* wr = &ws[k * H_MID + j0];
      a0 = fmaf(xv, wr[0], a0);
      a1 = fmaf(xv, wr[1], a1);
      a2 = fmaf(xv, wr[2], a2);
      a3 = fmaf(xv, wr[3], a3);
    }
    const int row = row0 + rl;
    const float dv = dinv[row];
    *(float4*)&m[(size_t)row * H_MID + j0] =
        make_float4(a0 * dv, a1 * dv, a2 * dv, a3 * dv);
  }
}

// ---------------- gather 16 feats: agg[n] = m[n] + sum_{s in adj(n)} m[s] ----------------
__global__ void k_gather16(const float* __restrict__ m, const int* __restrict__ rowptr,
                           const int* __restrict__ adj, float* __restrict__ agg, int N) {
  int t = blockIdx.x * 256 + threadIdx.x;
  int n = t >> 4, j = t & 15;
  if (n >= N) return;
  int beg = rowptr[n], end = rowptr[n + 1];
  float s = m[(size_t)n * 16 + j];  // self-loop
  int k = beg;
  for (; k + 4 <= end; k += 4) {
    int s0 = adj[k], s1 = adj[k + 1], s2 = adj[k + 2], s3 = adj[k + 3];
    float a = m[(size_t)s0 * 16 + j];
    float b = m[(size_t)s1 * 16 + j];
    float c = m[(size_t)s2 * 16 + j];
    float d = m[(size_t)s3 * 16 + j];
    s += (a + b) + (c + d);
  }
  for (; k < end; ++k) s += m[(size_t)adj[k] * 16 + j];
  agg[t] = s;
}

// ---------------- h2 = relu(hg*dinv + b1); hg <- g = (h2 @ Wend)*dinv (in place) -------
__global__ __launch_bounds__(256) void k_mid(
    float* hg, const float* __restrict__ dinv,
    const float* __restrict__ b1, const float* __restrict__ Wend, int N) {
  __shared__ float ws[H_MID * C_OUT];
  __shared__ float bs[H_MID];
  const int t = threadIdx.x;
  if (t < H_MID * C_OUT) ws[t] = Wend[t];
  if (t < H_MID) bs[t] = b1[t];
  __syncthreads();
  const int n = blockIdx.x * 256 + t;
  if (n >= N) return;
  const float dv = dinv[n];
  float h[H_MID];
  const float4* ag = (const float4*)(hg + (size_t)n * H_MID);
  #pragma unroll
  for (int q = 0; q < 4; ++q) {
    float4 v = ag[q];
    h[4*q+0] = fmaxf(fmaf(v.x, dv, bs[4*q+0]), 0.f);
    h[4*q+1] = fmaxf(fmaf(v.y, dv, bs[4*q+1]), 0.f);
    h[4*q+2] = fmaxf(fmaf(v.z, dv, bs[4*q+2]), 0.f);
    h[4*q+3] = fmaxf(fmaf(v.w, dv, bs[4*q+3]), 0.f);
  }
  float o[C_OUT];
  #pragma unroll
  for (int jj = 0; jj < C_OUT; ++jj) {
    float a = 0.f;
    #pragma unroll
    for (int k = 0; k < H_MID; ++k) a = fmaf(h[k], ws[k * C_OUT + jj], a);
    o[jj] = a * dv;
  }
  float2* gp = (float2*)(hg + (size_t)n * H_MID);
  #pragma unroll
  for (int q = 0; q < 5; ++q) gp[q] = make_float2(o[2*q], o[2*q+1]);
}

// ---------------- gather 10 feats + bias + log_softmax, fused ----------------
__global__ void k_gather10_final(const float* __restrict__ hg, const int* __restrict__ rowptr,
                                 const int* __restrict__ adj, const float* __restrict__ dinv,
                                 const float* __restrict__ bend, float* __restrict__ out, int N) {
  int t = blockIdx.x * 256 + threadIdx.x;
  int n = t >> 4, j = t & 15;
  if (n >= N) return;
  float s = 0.f;
  if (j < C_OUT) {
    int beg = rowptr[n], end = rowptr[n + 1];
    s = hg[(size_t)n * 16 + j];  // self-loop
    int k = beg;
    for (; k + 4 <= end; k += 4) {
      int s0 = adj[k], s1 = adj[k + 1], s2 = adj[k + 2], s3 = adj[k + 3];
      float a = hg[(size_t)s0 * 16 + j];
      float b = hg[(size_t)s1 * 16 + j];
      float c = hg[(size_t)s2 * 16 + j];
      float d = hg[(size_t)s3 * 16 + j];
      s += (a + b) + (c + d);
    }
    for (; k < end; ++k) s += hg[(size_t)adj[k] * 16 + j];
  }
  float v = (j < C_OUT) ? fmaf(s, dinv[n], bend[j]) : -INFINITY;
  float mx = v;
  #pragma unroll
  for (int w = 8; w; w >>= 1) mx = fmaxf(mx, __shfl_xor(mx, w, 16));
  float e = (j < C_OUT) ? __expf(v - mx) : 0.f;
  float ss = e;
  #pragma unroll
  for (int w = 8; w; w >>= 1) ss += __shfl_xor(ss, w, 16);
  if (j < C_OUT) out[(size_t)n * C_OUT + j] = v - (__logf(ss) + mx);
}

extern "C" void kernel_launch(void* const* d_in, const int* in_sizes, int n_in,
                              void* d_out, int out_size, void* d_ws, size_t ws_size,
                              hipStream_t stream) {
  // inputs: 0=x1 1=x2 2=W1 3=b1 4=W_end 5=b_end 6=edge_index1 7=edge_index2 8=skip
  // x1 / edge_index1 / skip are dead w.r.t. the returned output.
  const float* x2   = (const float*)d_in[1];
  const float* W1   = (const float*)d_in[2];
  const float* b1   = (const float*)d_in[3];
  const float* Wend = (const float*)d_in[4];
  const float* bend = (const float*)d_in[5];
  const int*   ei2  = (const int*)d_in[7];
  const int N = in_sizes[1] / F_IN;
  const int E = in_sizes[7] / 2;
  const int* src = ei2;
  const int* dst = ei2 + E;

  char* base = (char*)d_ws;
  size_t off = 0;
  auto alloc = [&](size_t bytes) -> void* {
    void* p = (void*)(base + off);
    off += ((bytes + 255) / 256) * 256;
    return p;
  };
  int*   deg    = (int*)  alloc((size_t)N * 4);
  int*   rowptr = (int*)  alloc(((size_t)N + 1) * 4);
  int*   cursor = (int*)  alloc((size_t)N * 4);
  int*   bsum   = (int*)  alloc(256 * 4);
  int*   adj    = (int*)  alloc((size_t)E * 4);
  float* dinv   = (float*)alloc((size_t)N * 4);
  float* m      = (float*)alloc((size_t)N * H_MID * 4);
  float* agg    = (float*)alloc((size_t)N * H_MID * 4);  // becomes g in k_mid

  const dim3 blk(256);
  const int gN  = (N + 255) / 256;
  const int gE  = (E + 255) / 256;
  const int nb  = (N + SCAN_TILE - 1) / SCAN_TILE;
  const int gNF = ((N * 16) + 255) / 256;

  hipLaunchKernelGGL(k_zero,      dim3(gN), blk, 0, stream, deg, N);
  hipLaunchKernelGGL(k_deg_count, dim3(gE), blk, 0, stream, dst, deg, E);
  hipLaunchKernelGGL(k_scan1,     dim3(nb), dim3(SCAN_BLOCK), 0, stream, deg, rowptr, dinv, bsum, N);
  hipLaunchKernelGGL(k_scan2,     dim3(1),  dim3(64), 0, stream, bsum, nb);
  hipLaunchKernelGGL(k_scan3,     dim3(gN), blk, 0, stream, rowptr, bsum, cursor, N, E);
  hipLaunchKernelGGL(k_fill,      dim3(gE), blk, 0, stream, src, dst, rowptr, cursor, adj, E);
  hipLaunchKernelGGL(k_gemv16,    dim3((N + 63) / 64), blk, 0, stream, x2, W1, dinv, m, N);
  hipLaunchKernelGGL(k_gather16,  dim3(gNF), blk, 0, stream, m, rowptr, adj, agg, N);
  hipLaunchKernelGGL(k_mid,       dim3(gN), blk, 0, stream, agg, dinv, b1, Wend, N);
  hipLaunchKernelGGL(k_gather10_final, dim3(gNF), blk, 0, stream,
                     agg, rowptr, adj, dinv, bend, (float*)d_out, N);
}

// Round 3
// 366.726 us; speedup vs baseline: 2.0459x; 1.4960x over previous
//
#include <hip/hip_runtime.h>
#include <math.h>

constexpr int F_IN  = 128;
constexpr int H_MID = 16;
constexpr int C_OUT = 10;

// ---- edge-partition parameters (assumes N < 2^17 = 131072; here N = 100000) ----
constexpr int NB    = 512;   // coarse buckets
constexpr int BSH   = 8;     // bucket = dst >> 8  (256 nodes / bucket)
constexpr int CHUNK = 8192;  // edges per partition block

// ---------------- pass 1: global bucket histogram ----------------
__global__ __launch_bounds__(256) void k_bhist(const int* __restrict__ dst,
                                               int* __restrict__ bhist, int E) {
  __shared__ int h[NB];
  const int t = threadIdx.x;
  for (int i = t; i < NB; i += 256) h[i] = 0;
  __syncthreads();
  const int base = blockIdx.x * CHUNK;
  const int lim  = min(CHUNK, E - base);
  for (int i = t; i < lim; i += 256) atomicAdd(&h[dst[base + i] >> BSH], 1);
  __syncthreads();
  for (int i = t; i < NB; i += 256)
    if (h[i]) atomicAdd(&bhist[i], h[i]);
}

// ---------------- pass 2: scan buckets (1 block) ----------------
__global__ __launch_bounds__(NB) void k_bscan(const int* __restrict__ bhist,
                                              int* __restrict__ gbbase,
                                              int* __restrict__ gcursor,
                                              int* __restrict__ rowptr, int N, int E) {
  __shared__ int sA[NB], sB[NB];
  const int t = threadIdx.x;
  const int v = bhist[t];
  sA[t] = v;
  __syncthreads();
  int* pa = sA; int* pb = sB;
  for (int off = 1; off < NB; off <<= 1) {
    pb[t] = pa[t] + ((t >= off) ? pa[t - off] : 0);
    __syncthreads();
    int* tmp = pa; pa = pb; pb = tmp;
  }
  const int incl = pa[t];
  gbbase[t]  = incl - v;
  gcursor[t] = incl - v;
  if (t == NB - 1) { gbbase[NB] = incl; rowptr[N] = E; }
}

// ---------------- pass 3: partition edges into bucket-grouped array ----------------
// packed entry: ((dst & 255) << 17) | src     (src < 2^17)
__global__ __launch_bounds__(256) void k_partition(
    const int* __restrict__ src, const int* __restrict__ dst,
    int* __restrict__ gcursor, int* __restrict__ epart, int E) {
  __shared__ int lbuf[CHUNK];       // 32 KB
  __shared__ int hist[NB];          // counts -> local cursor
  __shared__ int excl[NB + 1];
  __shared__ int gbase[NB];
  __shared__ int sA[NB], sB[NB];
  const int t = threadIdx.x;
  const int base = blockIdx.x * CHUNK;
  const int lim  = min(CHUNK, E - base);

  for (int i = t; i < NB; i += 256) hist[i] = 0;
  __syncthreads();
  for (int i = t; i < lim; i += 256) atomicAdd(&hist[dst[base + i] >> BSH], 1);
  __syncthreads();

  // block scan hist -> excl
  for (int i = t; i < NB; i += 256) sA[i] = hist[i];
  __syncthreads();
  int* pa = sA; int* pb = sB;
  for (int off = 1; off < NB; off <<= 1) {
    for (int i = t; i < NB; i += 256) pb[i] = pa[i] + ((i >= off) ? pa[i - off] : 0);
    __syncthreads();
    int* tmp = pa; pa = pb; pb = tmp;
  }
  for (int i = t; i < NB; i += 256) excl[i] = pa[i] - hist[i];
  if (t == 0) excl[NB] = pa[NB - 1];
  __syncthreads();

  // reserve global space per bucket; convert hist -> local cursor
  for (int b = t; b < NB; b += 256) {
    const int cnt = excl[b + 1] - excl[b];
    if (cnt > 0) gbase[b] = atomicAdd(&gcursor[b], cnt);
    hist[b] = excl[b];
  }
  __syncthreads();

  // place into LDS, bucket-grouped
  for (int i = t; i < lim; i += 256) {
    const int d = dst[base + i];
    const int b = d >> BSH;
    const int lpos = atomicAdd(&hist[b], 1);
    lbuf[lpos] = ((d & ((1 << BSH) - 1)) << 17) | src[base + i];
  }
  __syncthreads();

  // copy out: consecutive i within a bucket -> consecutive global addresses
  for (int i = t; i < lim; i += 256) {
    int lo = 0, hi = NB;
    while (hi - lo > 1) { const int mid = (lo + hi) >> 1; if (excl[mid] <= i) lo = mid; else hi = mid; }
    epart[gbase[lo] + (i - excl[lo])] = lbuf[i];
  }
}

// ---------------- pass 4: per-bucket placement + deg/rowptr/dinv ----------------
__global__ __launch_bounds__(256) void k_place(
    const int* __restrict__ epart, const int* __restrict__ gbbase,
    int* __restrict__ adj, int* __restrict__ rowptr, float* __restrict__ dinv,
    int N) {
  __shared__ int ldeg[256];
  __shared__ int sA[256], sB[256];
  __shared__ int cur[256];
  const int b = blockIdx.x, t = threadIdx.x;
  const int e0 = gbbase[b], e1 = gbbase[b + 1];
  ldeg[t] = 0;
  __syncthreads();
  for (int i = e0 + t; i < e1; i += 256) atomicAdd(&ldeg[epart[i] >> 17], 1);
  __syncthreads();
  const int myDeg = ldeg[t];
  // exclusive scan of ldeg
  sA[t] = myDeg;
  __syncthreads();
  int* pa = sA; int* pb = sB;
  for (int off = 1; off < 256; off <<= 1) {
    pb[t] = pa[t] + ((t >= off) ? pa[t - off] : 0);
    __syncthreads();
    int* tmp = pa; pa = pb; pb = tmp;
  }
  const int lbase = pa[t] - myDeg;
  cur[t] = lbase;
  const int node = (b << BSH) + t;
  if (node < N) {
    rowptr[node] = e0 + lbase;
    dinv[node]   = rsqrtf((float)(myDeg + 1));  // +1 self-loop
  }
  __syncthreads();
  for (int i = e0 + t; i < e1; i += 256) {
    const int p = epart[i];
    const int dl = p >> 17;
    const int pos = atomicAdd(&cur[dl], 1);
    adj[e0 + pos] = p & 0x1FFFF;
  }
}

// ---------------- m = (x2 @ W1) * dinv[row] ----------------
__global__ __launch_bounds__(256) void k_gemv16(
    const float* __restrict__ x, const float* __restrict__ W,
    const float* __restrict__ dinv, float* __restrict__ m, int N) {
  __shared__ float ws[F_IN * H_MID];   // 8 KB
  __shared__ float xs[64 * 132];       // pad 128->132
  const int t = threadIdx.x;
  for (int i = t; i < F_IN * H_MID; i += 256) ws[i] = W[i];
  const int row0 = blockIdx.x * 64;
  const int rows = min(64, N - row0);
  const float4* xg = (const float4*)(x + (size_t)row0 * F_IN);
  for (int i = t; i < rows * 32; i += 256) {
    int rl = i >> 5, c = i & 31;
    float4 v = xg[rl * 32 + c];
    *(float4*)&xs[rl * 132 + c * 4] = v;
  }
  __syncthreads();
  const int rl = t >> 2;
  const int j0 = (t & 3) * 4;
  if (rl < rows) {
    float a0 = 0.f, a1 = 0.f, a2 = 0.f, a3 = 0.f;
    const float* xr = &xs[rl * 132];
    #pragma unroll
    for (int k = 0; k < F_IN; ++k) {
      const float xv = xr[k];
      const float* wr = &ws[k * H_MID + j0];
      a0 = fmaf(xv, wr[0], a0);
      a1 = fmaf(xv, wr[1], a1);
      a2 = fmaf(xv, wr[2], a2);
      a3 = fmaf(xv, wr[3], a3);
    }
    const int row = row0 + rl;
    const float dv = dinv[row];
    *(float4*)&m[(size_t)row * H_MID + j0] =
        make_float4(a0 * dv, a1 * dv, a2 * dv, a3 * dv);
  }
}

// ---------------- gather 16 feats ----------------
__global__ void k_gather16(const float* __restrict__ m, const int* __restrict__ rowptr,
                           const int* __restrict__ adj, float* __restrict__ agg, int N) {
  int t = blockIdx.x * 256 + threadIdx.x;
  int n = t >> 4, j = t & 15;
  if (n >= N) return;
  int beg = rowptr[n], end = rowptr[n + 1];
  float s = m[(size_t)n * 16 + j];  // self-loop
  int k = beg;
  for (; k + 4 <= end; k += 4) {
    int s0 = adj[k], s1 = adj[k + 1], s2 = adj[k + 2], s3 = adj[k + 3];
    float a = m[(size_t)s0 * 16 + j];
    float b = m[(size_t)s1 * 16 + j];
    float c = m[(size_t)s2 * 16 + j];
    float d = m[(size_t)s3 * 16 + j];
    s += (a + b) + (c + d);
  }
  for (; k < end; ++k) s += m[(size_t)adj[k] * 16 + j];
  agg[t] = s;
}

// ---------------- h2 = relu(hg*dinv + b1); hg <- (h2 @ Wend)*dinv ----------------
__global__ __launch_bounds__(256) void k_mid(
    float* hg, const float* __restrict__ dinv,
    const float* __restrict__ b1, const float* __restrict__ Wend, int N) {
  __shared__ float ws[H_MID * C_OUT];
  __shared__ float bs[H_MID];
  const int t = threadIdx.x;
  if (t < H_MID * C_OUT) ws[t] = Wend[t];
  if (t < H_MID) bs[t] = b1[t];
  __syncthreads();
  const int n = blockIdx.x * 256 + t;
  if (n >= N) return;
  const float dv = dinv[n];
  float h[H_MID];
  const float4* ag = (const float4*)(hg + (size_t)n * H_MID);
  #pragma unroll
  for (int q = 0; q < 4; ++q) {
    float4 v = ag[q];
    h[4*q+0] = fmaxf(fmaf(v.x, dv, bs[4*q+0]), 0.f);
    h[4*q+1] = fmaxf(fmaf(v.y, dv, bs[4*q+1]), 0.f);
    h[4*q+2] = fmaxf(fmaf(v.z, dv, bs[4*q+2]), 0.f);
    h[4*q+3] = fmaxf(fmaf(v.w, dv, bs[4*q+3]), 0.f);
  }
  float o[C_OUT];
  #pragma unroll
  for (int jj = 0; jj < C_OUT; ++jj) {
    float a = 0.f;
    #pragma unroll
    for (int k = 0; k < H_MID; ++k) a = fmaf(h[k], ws[k * C_OUT + jj], a);
    o[jj] = a * dv;
  }
  float2* gp = (float2*)(hg + (size_t)n * H_MID);
  #pragma unroll
  for (int q = 0; q < 5; ++q) gp[q] = make_float2(o[2*q], o[2*q+1]);
}

// ---------------- gather 10 feats + bias + log_softmax ----------------
__global__ void k_gather10_final(const float* __restrict__ hg, const int* __restrict__ rowptr,
                                 const int* __restrict__ adj, const float* __restrict__ dinv,
                                 const float* __restrict__ bend, float* __restrict__ out, int N) {
  int t = blockIdx.x * 256 + threadIdx.x;
  int n = t >> 4, j = t & 15;
  if (n >= N) return;
  float s = 0.f;
  if (j < C_OUT) {
    int beg = rowptr[n], end = rowptr[n + 1];
    s = hg[(size_t)n * 16 + j];  // self-loop
    int k = beg;
    for (; k + 4 <= end; k += 4) {
      int s0 = adj[k], s1 = adj[k + 1], s2 = adj[k + 2], s3 = adj[k + 3];
      float a = hg[(size_t)s0 * 16 + j];
      float b = hg[(size_t)s1 * 16 + j];
      float c = hg[(size_t)s2 * 16 + j];
      float d = hg[(size_t)s3 * 16 + j];
      s += (a + b) + (c + d);
    }
    for (; k < end; ++k) s += hg[(size_t)adj[k] * 16 + j];
  }
  float v = (j < C_OUT) ? fmaf(s, dinv[n], bend[j]) : -INFINITY;
  float mx = v;
  #pragma unroll
  for (int w = 8; w; w >>= 1) mx = fmaxf(mx, __shfl_xor(mx, w, 16));
  float e = (j < C_OUT) ? __expf(v - mx) : 0.f;
  float ss = e;
  #pragma unroll
  for (int w = 8; w; w >>= 1) ss += __shfl_xor(ss, w, 16);
  if (j < C_OUT) out[(size_t)n * C_OUT + j] = v - (__logf(ss) + mx);
}

extern "C" void kernel_launch(void* const* d_in, const int* in_sizes, int n_in,
                              void* d_out, int out_size, void* d_ws, size_t ws_size,
                              hipStream_t stream) {
  // inputs: 0=x1 1=x2 2=W1 3=b1 4=W_end 5=b_end 6=edge_index1 7=edge_index2 8=skip
  // x1 / edge_index1 / skip are dead w.r.t. the returned output.
  const float* x2   = (const float*)d_in[1];
  const float* W1   = (const float*)d_in[2];
  const float* b1   = (const float*)d_in[3];
  const float* Wend = (const float*)d_in[4];
  const float* bend = (const float*)d_in[5];
  const int*   ei2  = (const int*)d_in[7];
  const int N = in_sizes[1] / F_IN;
  const int E = in_sizes[7] / 2;
  const int* src = ei2;
  const int* dst = ei2 + E;

  char* base = (char*)d_ws;
  size_t off = 0;
  auto alloc = [&](size_t bytes) -> void* {
    void* p = (void*)(base + off);
    off += ((bytes + 255) / 256) * 256;
    return p;
  };
  int*   bhist   = (int*)  alloc((size_t)NB * 4);
  int*   gbbase  = (int*)  alloc(((size_t)NB + 1) * 4);
  int*   gcursor = (int*)  alloc((size_t)NB * 4);
  int*   rowptr  = (int*)  alloc(((size_t)N + 1) * 4);
  float* dinv    = (float*)alloc((size_t)N * 4);
  int*   adj     = (int*)  alloc((size_t)E * 4);
  float* m       = (float*)alloc((size_t)N * H_MID * 4);
  float* agg     = (float*)alloc((size_t)N * H_MID * 4);
  // epart (E ints = 12.8 MB) aliases m+agg (2*N*16 floats = 12.8 MB):
  // it is dead before k_gemv16 writes m.
  int*   epart   = (int*)m;

  const dim3 blk(256);
  const int gN   = (N + 255) / 256;
  const int gEC  = (E + CHUNK - 1) / CHUNK;
  const int gNB  = (N + 255) >> BSH;      // buckets actually covering nodes
  const int gNF  = ((N * 16) + 255) / 256;

  hipMemsetAsync(bhist, 0, (size_t)NB * 4, stream);
  hipLaunchKernelGGL(k_bhist,     dim3(gEC), blk, 0, stream, dst, bhist, E);
  hipLaunchKernelGGL(k_bscan,     dim3(1), dim3(NB), 0, stream, bhist, gbbase, gcursor, rowptr, N, E);
  hipLaunchKernelGGL(k_partition, dim3(gEC), blk, 0, stream, src, dst, gcursor, epart, E);
  hipLaunchKernelGGL(k_place,     dim3(gNB), blk, 0, stream, epart, gbbase, adj, rowptr, dinv, N);
  hipLaunchKernelGGL(k_gemv16,    dim3((N + 63) / 64), blk, 0, stream, x2, W1, dinv, m, N);
  hipLaunchKernelGGL(k_gather16,  dim3(gNF), blk, 0, stream, m, rowptr, adj, agg, N);
  hipLaunchKernelGGL(k_mid,       dim3(gN), blk, 0, stream, agg, dinv, b1, Wend, N);
  hipLaunchKernelGGL(k_gather10_final, dim3(gNF), blk, 0, stream,
                     agg, rowptr, adj, dinv, bend, (float*)d_out, N);
}